// Round 1
// baseline (870.885 us; speedup 1.0000x reference)
//
#include <hip/hip_runtime.h>
#include <math.h>
#include <stdint.h>

// ---------------------------------------------------------------------------
// GATv2 3-layer network on MI355X.
// Pipeline per call:
//   1) Build CSR by dst (deg count -> exclusive scan -> scatter). dst includes
//      self-loops (edge i>=E has src=dst=i-E).
//   2) Per layer: xl = h@Wl+bl, xr = h@Wr+br (fp32 tiled GEMM),
//      then one wave per dst node runs online-softmax attention aggregation
//      (single gather of xl[src] per edge, no atomics).
//   3) Classifier GEMV per row.
// ---------------------------------------------------------------------------

__global__ void zero_int_kernel(int* __restrict__ p, int n) {
  int i = blockIdx.x * blockDim.x + threadIdx.x;
  if (i < n) p[i] = 0;
}

__global__ void deg_count_kernel(const int* __restrict__ dst, int E, int n,
                                 int* __restrict__ deg) {
  int i = blockIdx.x * blockDim.x + threadIdx.x;
  int tot = E + n;
  if (i < tot) {
    int d = (i < E) ? dst[i] : (i - E);
    atomicAdd(&deg[d], 1);
  }
}

__global__ __launch_bounds__(1024) void scan_excl_kernel(
    const int* __restrict__ deg, int* __restrict__ row_ptr, int n) {
  __shared__ int sm[1024];
  __shared__ int carry_sm;
  if (threadIdx.x == 0) carry_sm = 0;
  __syncthreads();
  for (int base = 0; base < n; base += 1024) {
    int i = base + threadIdx.x;
    int v = (i < n) ? deg[i] : 0;
    sm[threadIdx.x] = v;
    __syncthreads();
    for (int off = 1; off < 1024; off <<= 1) {
      int t = (threadIdx.x >= off) ? sm[threadIdx.x - off] : 0;
      __syncthreads();
      sm[threadIdx.x] += t;
      __syncthreads();
    }
    int incl = sm[threadIdx.x];
    int carry = carry_sm;
    if (i < n) row_ptr[i] = carry + incl - v;  // exclusive
    __syncthreads();
    if (threadIdx.x == 1023) carry_sm += sm[1023];
    __syncthreads();
  }
  if (threadIdx.x == 0) row_ptr[n] = carry_sm;
}

__global__ void copy_int_kernel(const int* __restrict__ a, int* __restrict__ b,
                                int n) {
  int i = blockIdx.x * blockDim.x + threadIdx.x;
  if (i < n) b[i] = a[i];
}

__global__ void scatter_kernel(const int* __restrict__ src,
                               const int* __restrict__ dst, int E, int n,
                               int* __restrict__ cursor,
                               int* __restrict__ col_src) {
  int i = blockIdx.x * blockDim.x + threadIdx.x;
  int tot = E + n;
  if (i < tot) {
    int s = (i < E) ? src[i] : (i - E);
    int d = (i < E) ? dst[i] : (i - E);
    int slot = atomicAdd(&cursor[d], 1);
    col_src[slot] = s;
  }
}

// Y[M][DOUT] = X[M][128] @ W[128][DOUT] + B.  64-row tile, 256 threads,
// each thread computes 4 rows x (8*COLG) cols.
template <int DOUT>
__global__ __launch_bounds__(256) void gemm128_bias_kernel(
    const float* __restrict__ X, const float* __restrict__ W,
    const float* __restrict__ B, float* __restrict__ Y, int M) {
  constexpr int DIN = 128;
  constexpr int KT = 32;
  constexpr int COLG = DOUT / 128;
  __shared__ float Xs[64][36];  // stride 36 -> 2-way (free) bank aliasing
  __shared__ float Ws[KT][DOUT];
  const int tid = threadIdx.x;
  const int tx = tid & 15;
  const int ty = (tid >> 4) & 15;
  const int r0 = ty * 4;
  const int rbase = blockIdx.x * 64;

  float acc[4][COLG * 8];
#pragma unroll
  for (int i = 0; i < 4; ++i)
#pragma unroll
    for (int j = 0; j < COLG * 8; ++j) acc[i][j] = 0.f;

  for (int k0 = 0; k0 < DIN; k0 += KT) {
    // stage X tile [64][32]
#pragma unroll
    for (int t = 0; t < 2; ++t) {
      int idx = tid + t * 256;
      int r = idx >> 3;
      int kq = idx & 7;
      int gr = rbase + r;
      float4 v = make_float4(0.f, 0.f, 0.f, 0.f);
      if (gr < M)
        v = *reinterpret_cast<const float4*>(X + (size_t)gr * DIN + k0 + kq * 4);
      *reinterpret_cast<float4*>(&Xs[r][kq * 4]) = v;
    }
    // stage W tile [32][DOUT]
    constexpr int WLOADS = KT * DOUT / 4 / 256;
#pragma unroll
    for (int t = 0; t < WLOADS; ++t) {
      int idx = tid + t * 256;
      int wr = idx / (DOUT / 4);
      int wcq = idx % (DOUT / 4);
      *reinterpret_cast<float4*>(&Ws[wr][wcq * 4]) =
          *reinterpret_cast<const float4*>(W + (size_t)(k0 + wr) * DOUT + wcq * 4);
    }
    __syncthreads();
#pragma unroll
    for (int kk = 0; kk < KT; kk += 4) {
      float4 a[4];
#pragma unroll
      for (int i = 0; i < 4; ++i)
        a[i] = *reinterpret_cast<const float4*>(&Xs[r0 + i][kk]);
#pragma unroll
      for (int g = 0; g < COLG; ++g) {
#pragma unroll
        for (int u = 0; u < 4; ++u) {
          float4 b0 = *reinterpret_cast<const float4*>(&Ws[kk + u][g * 128 + tx * 8]);
          float4 b1 =
              *reinterpret_cast<const float4*>(&Ws[kk + u][g * 128 + tx * 8 + 4]);
#pragma unroll
          for (int i = 0; i < 4; ++i) {
            float av = (u == 0) ? a[i].x : (u == 1) ? a[i].y : (u == 2) ? a[i].z : a[i].w;
            acc[i][g * 8 + 0] = fmaf(av, b0.x, acc[i][g * 8 + 0]);
            acc[i][g * 8 + 1] = fmaf(av, b0.y, acc[i][g * 8 + 1]);
            acc[i][g * 8 + 2] = fmaf(av, b0.z, acc[i][g * 8 + 2]);
            acc[i][g * 8 + 3] = fmaf(av, b0.w, acc[i][g * 8 + 3]);
            acc[i][g * 8 + 4] = fmaf(av, b1.x, acc[i][g * 8 + 4]);
            acc[i][g * 8 + 5] = fmaf(av, b1.y, acc[i][g * 8 + 5]);
            acc[i][g * 8 + 6] = fmaf(av, b1.z, acc[i][g * 8 + 6]);
            acc[i][g * 8 + 7] = fmaf(av, b1.w, acc[i][g * 8 + 7]);
          }
        }
      }
    }
    __syncthreads();
  }
#pragma unroll
  for (int i = 0; i < 4; ++i) {
    int gr = rbase + r0 + i;
    if (gr < M) {
#pragma unroll
      for (int g = 0; g < COLG; ++g) {
        int c = g * 128 + tx * 8;
        float4 o0, o1;
        o0.x = acc[i][g * 8 + 0] + B[c + 0];
        o0.y = acc[i][g * 8 + 1] + B[c + 1];
        o0.z = acc[i][g * 8 + 2] + B[c + 2];
        o0.w = acc[i][g * 8 + 3] + B[c + 3];
        o1.x = acc[i][g * 8 + 4] + B[c + 4];
        o1.y = acc[i][g * 8 + 5] + B[c + 5];
        o1.z = acc[i][g * 8 + 6] + B[c + 6];
        o1.w = acc[i][g * 8 + 7] + B[c + 7];
        *reinterpret_cast<float4*>(Y + (size_t)gr * DOUT + c) = o0;
        *reinterpret_cast<float4*>(Y + (size_t)gr * DOUT + c + 4) = o1;
      }
    }
  }
}

// One wave per dst node: online-softmax attention + aggregation, single pass.
template <int DOUT, bool RELU>
__global__ __launch_bounds__(256) void attn_kernel(
    const float* __restrict__ xl, const float* __restrict__ xr,
    const float* __restrict__ att, const float* __restrict__ bias,
    const int* __restrict__ row_ptr, const int* __restrict__ col_src,
    float* __restrict__ out, int M) {
  constexpr int VPL = DOUT / 64;
  int wid = (int)((blockIdx.x * blockDim.x + threadIdx.x) >> 6);
  int lane = threadIdx.x & 63;
  if (wid >= M) return;

  float attr[VPL], xrr[VPL], acc[VPL];
#pragma unroll
  for (int v = 0; v < VPL; ++v) {
    attr[v] = att[v * 64 + lane];
    xrr[v] = xr[(size_t)wid * DOUT + v * 64 + lane];
    acc[v] = 0.f;
  }
  float m = -INFINITY, s = 0.f;
  int e0 = row_ptr[wid], e1 = row_ptr[wid + 1];
  for (int j = e0; j < e1; ++j) {
    int src = col_src[j];
    float xv[VPL];
    float p = 0.f;
#pragma unroll
    for (int v = 0; v < VPL; ++v) {
      float xlv = xl[(size_t)src * DOUT + v * 64 + lane];
      xv[v] = xlv;
      float t = xlv + xrr[v];
      t = fmaxf(t, 0.2f * t);  // leaky_relu, slope 0.2
      p = fmaf(attr[v], t, p);
    }
#pragma unroll
    for (int off = 32; off > 0; off >>= 1) p += __shfl_xor(p, off, 64);
    float nm = fmaxf(m, p);
    float scale = __expf(m - nm);  // exp(-inf)=0 on first edge
    float pe = __expf(p - nm);
    s = s * scale + pe;
#pragma unroll
    for (int v = 0; v < VPL; ++v) acc[v] = fmaf(acc[v], scale, pe * xv[v]);
    m = nm;
  }
  float inv = 1.f / s;  // degree >= 1 (self-loops)
#pragma unroll
  for (int v = 0; v < VPL; ++v) {
    float o = fmaf(acc[v], inv, bias[v * 64 + lane]);
    if (RELU) o = fmaxf(o, 0.f);
    out[(size_t)wid * DOUT + v * 64 + lane] = o;
  }
}

// out[M][40] = H[M][256] @ WC[256][40] + BC.  One wave per row.
__global__ __launch_bounds__(256) void classifier_kernel(
    const float* __restrict__ H, const float* __restrict__ WC,
    const float* __restrict__ BC, float* __restrict__ out, int M) {
  __shared__ float rb[4][260];
  int wl = threadIdx.x >> 6;
  int lane = threadIdx.x & 63;
  int row = blockIdx.x * 4 + wl;
  bool valid = row < M;
  const float* hr = H + (size_t)(valid ? row : 0) * 256;
  float4 v = valid ? *reinterpret_cast<const float4*>(hr + lane * 4)
                   : make_float4(0.f, 0.f, 0.f, 0.f);
  *reinterpret_cast<float4*>(&rb[wl][lane * 4]) = v;
  __syncthreads();
  if (valid && lane < 40) {
    float acc = 0.f;
#pragma unroll 8
    for (int k = 0; k < 256; ++k) acc = fmaf(rb[wl][k], WC[k * 40 + lane], acc);
    out[(size_t)row * 40 + lane] = acc + BC[lane];
  }
}

extern "C" void kernel_launch(void* const* d_in, const int* in_sizes, int n_in,
                              void* d_out, int out_size, void* d_ws,
                              size_t ws_size, hipStream_t stream) {
  const float* x = (const float*)d_in[0];
  const int* ei = (const int*)d_in[1];
  const float* w1l = (const float*)d_in[2];
  const float* b1l = (const float*)d_in[3];
  const float* w1r = (const float*)d_in[4];
  const float* b1r = (const float*)d_in[5];
  const float* a1 = (const float*)d_in[6];
  const float* o1 = (const float*)d_in[7];
  const float* w2l = (const float*)d_in[8];
  const float* b2l = (const float*)d_in[9];
  const float* w2r = (const float*)d_in[10];
  const float* b2r = (const float*)d_in[11];
  const float* a2 = (const float*)d_in[12];
  const float* o2 = (const float*)d_in[13];
  const float* w3l = (const float*)d_in[14];
  const float* b3l = (const float*)d_in[15];
  const float* w3r = (const float*)d_in[16];
  const float* b3r = (const float*)d_in[17];
  const float* a3 = (const float*)d_in[18];
  const float* o3 = (const float*)d_in[19];
  const float* wc = (const float*)d_in[20];
  const float* bc = (const float*)d_in[21];
  float* out = (float*)d_out;

  const int n = in_sizes[0] / 128;  // 50000
  const int E = in_sizes[1] / 2;    // 800000
  const int tot = E + n;            // with self-loops

  // workspace layout
  char* p = (char*)d_ws;
  int* row_ptr = (int*)p;
  p += (size_t)(n + 1) * 4;
  int* cursor = (int*)p;  // doubles as deg
  p += (size_t)n * 4;
  int* col_src = (int*)p;
  p += (size_t)tot * 4;
  p = (char*)(((uintptr_t)p + 255) & ~(uintptr_t)255);
  float* bufA = (float*)p;
  p += (size_t)n * 256 * 4;
  float* bufB = (float*)p;
  p += (size_t)n * 256 * 4;
  float* bufC = (float*)p;

  int* deg = cursor;
  const int TPB = 256;

  // CSR build (dst is layer-invariant -> built once per call)
  zero_int_kernel<<<(n + TPB - 1) / TPB, TPB, 0, stream>>>(deg, n);
  deg_count_kernel<<<(tot + TPB - 1) / TPB, TPB, 0, stream>>>(ei + E, E, n, deg);
  scan_excl_kernel<<<1, 1024, 0, stream>>>(deg, row_ptr, n);
  copy_int_kernel<<<(n + TPB - 1) / TPB, TPB, 0, stream>>>(row_ptr, cursor, n);
  scatter_kernel<<<(tot + TPB - 1) / TPB, TPB, 0, stream>>>(ei, ei + E, E, n,
                                                            cursor, col_src);

  const int gemmGrid = (n + 63) / 64;
  const int waveGrid = (n + 3) / 4;

  // Layer 1 (128 -> 128) + ReLU
  gemm128_bias_kernel<128><<<gemmGrid, TPB, 0, stream>>>(x, w1l, b1l, bufB, n);
  gemm128_bias_kernel<128><<<gemmGrid, TPB, 0, stream>>>(x, w1r, b1r, bufC, n);
  attn_kernel<128, true><<<waveGrid, TPB, 0, stream>>>(bufB, bufC, a1, o1,
                                                       row_ptr, col_src, bufA, n);
  // Layer 2 (128 -> 128) + ReLU
  gemm128_bias_kernel<128><<<gemmGrid, TPB, 0, stream>>>(bufA, w2l, b2l, bufB, n);
  gemm128_bias_kernel<128><<<gemmGrid, TPB, 0, stream>>>(bufA, w2r, b2r, bufC, n);
  attn_kernel<128, true><<<waveGrid, TPB, 0, stream>>>(bufB, bufC, a2, o2,
                                                       row_ptr, col_src, bufA, n);
  // Layer 3 (128 -> 256), no ReLU
  gemm128_bias_kernel<256><<<gemmGrid, TPB, 0, stream>>>(bufA, w3l, b3l, bufB, n);
  gemm128_bias_kernel<256><<<gemmGrid, TPB, 0, stream>>>(bufA, w3r, b3r, bufC, n);
  attn_kernel<256, false><<<waveGrid, TPB, 0, stream>>>(bufB, bufC, a3, o3,
                                                        row_ptr, col_src, bufA, n);
  // Classifier (256 -> 40)
  classifier_kernel<<<waveGrid, TPB, 0, stream>>>(bufA, wc, bc, out, n);
}

// Round 2
// 678.027 us; speedup vs baseline: 1.2844x; 1.2844x over previous
//
#include <hip/hip_runtime.h>
#include <math.h>
#include <stdint.h>

// ---------------------------------------------------------------------------
// GATv2 3-layer network on MI355X.
//   1) CSR build by dst (deg count -> 3-kernel scan -> scatter).
//   2) Per layer: xl=h@Wl+bl, xr=h@Wr+br (fp32 tiled GEMM), then attention:
//      one wave per dst node, 4x 16-lane edge groups with independent
//      online-softmax state + 1-edge prefetch (high MLP), merged at the end.
//   3) Classifier GEMV per row.
// ---------------------------------------------------------------------------

__global__ void zero_int_kernel(int* __restrict__ p, int n) {
  int i = blockIdx.x * blockDim.x + threadIdx.x;
  if (i < n) p[i] = 0;
}

__global__ void deg_count_kernel(const int* __restrict__ dst, int E, int n,
                                 int* __restrict__ deg) {
  int i = blockIdx.x * blockDim.x + threadIdx.x;
  int tot = E + n;
  if (i < tot) {
    int d = (i < E) ? dst[i] : (i - E);
    atomicAdd(&deg[d], 1);
  }
}

// 3-phase exclusive scan over deg[n], chunk=1024. nchunks must be <= 64.
__global__ __launch_bounds__(256) void block_sum_kernel(
    const int* __restrict__ deg, int n, int* __restrict__ partial) {
  __shared__ int sm[256];
  int base = blockIdx.x * 1024;
  int t = threadIdx.x;
  int sum = 0;
#pragma unroll
  for (int k = 0; k < 4; ++k) {
    int i = base + k * 256 + t;
    sum += (i < n) ? deg[i] : 0;
  }
  sm[t] = sum;
  __syncthreads();
  for (int off = 128; off > 0; off >>= 1) {
    if (t < off) sm[t] += sm[t + off];
    __syncthreads();
  }
  if (t == 0) partial[blockIdx.x] = sm[0];
}

__global__ void scan_partial_kernel(int* __restrict__ partial, int nchunks) {
  int lane = threadIdx.x;  // 64 threads
  int v = (lane < nchunks) ? partial[lane] : 0;
#pragma unroll
  for (int off = 1; off < 64; off <<= 1) {
    int u = __shfl_up(v, off, 64);
    if (lane >= off) v += u;
  }
  int ex = __shfl_up(v, 1, 64);
  if (lane == 0) ex = 0;
  if (lane < nchunks) partial[lane] = ex;
}

__global__ __launch_bounds__(1024) void block_scan_kernel(
    const int* __restrict__ deg, const int* __restrict__ partial,
    int* __restrict__ row_ptr, int* __restrict__ cursor, int n) {
  __shared__ int sm[1024];
  int i = blockIdx.x * 1024 + threadIdx.x;
  int v = (i < n) ? deg[i] : 0;
  sm[threadIdx.x] = v;
  __syncthreads();
  for (int off = 1; off < 1024; off <<= 1) {
    int t = (threadIdx.x >= off) ? sm[threadIdx.x - off] : 0;
    __syncthreads();
    sm[threadIdx.x] += t;
    __syncthreads();
  }
  int excl = partial[blockIdx.x] + sm[threadIdx.x] - v;
  if (i < n) {
    row_ptr[i] = excl;
    cursor[i] = excl;
  }
  if (i == n - 1) row_ptr[n] = excl + v;
}

__global__ void scatter_kernel(const int* __restrict__ src,
                               const int* __restrict__ dst, int E, int n,
                               int* __restrict__ cursor,
                               int* __restrict__ col_src) {
  int i = blockIdx.x * blockDim.x + threadIdx.x;
  int tot = E + n;
  if (i < tot) {
    int s = (i < E) ? src[i] : (i - E);
    int d = (i < E) ? dst[i] : (i - E);
    int slot = atomicAdd(&cursor[d], 1);
    col_src[slot] = s;
  }
}

// Y[M][DOUT] = X[M][128] @ W[128][DOUT] + B.  64-row tile, 256 threads.
template <int DOUT>
__global__ __launch_bounds__(256) void gemm128_bias_kernel(
    const float* __restrict__ X, const float* __restrict__ W,
    const float* __restrict__ B, float* __restrict__ Y, int M) {
  constexpr int DIN = 128;
  constexpr int KT = 32;
  constexpr int COLG = DOUT / 128;
  __shared__ float Xs[64][36];
  __shared__ float Ws[KT][DOUT];
  const int tid = threadIdx.x;
  const int tx = tid & 15;
  const int ty = (tid >> 4) & 15;
  const int r0 = ty * 4;
  const int rbase = blockIdx.x * 64;

  float acc[4][COLG * 8];
#pragma unroll
  for (int i = 0; i < 4; ++i)
#pragma unroll
    for (int j = 0; j < COLG * 8; ++j) acc[i][j] = 0.f;

  for (int k0 = 0; k0 < DIN; k0 += KT) {
#pragma unroll
    for (int t = 0; t < 2; ++t) {
      int idx = tid + t * 256;
      int r = idx >> 3;
      int kq = idx & 7;
      int gr = rbase + r;
      float4 v = make_float4(0.f, 0.f, 0.f, 0.f);
      if (gr < M)
        v = *reinterpret_cast<const float4*>(X + (size_t)gr * DIN + k0 + kq * 4);
      *reinterpret_cast<float4*>(&Xs[r][kq * 4]) = v;
    }
    constexpr int WLOADS = KT * DOUT / 4 / 256;
#pragma unroll
    for (int t = 0; t < WLOADS; ++t) {
      int idx = tid + t * 256;
      int wr = idx / (DOUT / 4);
      int wcq = idx % (DOUT / 4);
      *reinterpret_cast<float4*>(&Ws[wr][wcq * 4]) =
          *reinterpret_cast<const float4*>(W + (size_t)(k0 + wr) * DOUT + wcq * 4);
    }
    __syncthreads();
#pragma unroll
    for (int kk = 0; kk < KT; kk += 4) {
      float4 a[4];
#pragma unroll
      for (int i = 0; i < 4; ++i)
        a[i] = *reinterpret_cast<const float4*>(&Xs[r0 + i][kk]);
#pragma unroll
      for (int g = 0; g < COLG; ++g) {
#pragma unroll
        for (int u = 0; u < 4; ++u) {
          float4 b0 = *reinterpret_cast<const float4*>(&Ws[kk + u][g * 128 + tx * 8]);
          float4 b1 =
              *reinterpret_cast<const float4*>(&Ws[kk + u][g * 128 + tx * 8 + 4]);
#pragma unroll
          for (int i = 0; i < 4; ++i) {
            float av = (u == 0) ? a[i].x : (u == 1) ? a[i].y : (u == 2) ? a[i].z : a[i].w;
            acc[i][g * 8 + 0] = fmaf(av, b0.x, acc[i][g * 8 + 0]);
            acc[i][g * 8 + 1] = fmaf(av, b0.y, acc[i][g * 8 + 1]);
            acc[i][g * 8 + 2] = fmaf(av, b0.z, acc[i][g * 8 + 2]);
            acc[i][g * 8 + 3] = fmaf(av, b0.w, acc[i][g * 8 + 3]);
            acc[i][g * 8 + 4] = fmaf(av, b1.x, acc[i][g * 8 + 4]);
            acc[i][g * 8 + 5] = fmaf(av, b1.y, acc[i][g * 8 + 5]);
            acc[i][g * 8 + 6] = fmaf(av, b1.z, acc[i][g * 8 + 6]);
            acc[i][g * 8 + 7] = fmaf(av, b1.w, acc[i][g * 8 + 7]);
          }
        }
      }
    }
    __syncthreads();
  }
#pragma unroll
  for (int i = 0; i < 4; ++i) {
    int gr = rbase + r0 + i;
    if (gr < M) {
#pragma unroll
      for (int g = 0; g < COLG; ++g) {
        int c = g * 128 + tx * 8;
        float4 o0, o1;
        o0.x = acc[i][g * 8 + 0] + B[c + 0];
        o0.y = acc[i][g * 8 + 1] + B[c + 1];
        o0.z = acc[i][g * 8 + 2] + B[c + 2];
        o0.w = acc[i][g * 8 + 3] + B[c + 3];
        o1.x = acc[i][g * 8 + 4] + B[c + 4];
        o1.y = acc[i][g * 8 + 5] + B[c + 5];
        o1.z = acc[i][g * 8 + 6] + B[c + 6];
        o1.w = acc[i][g * 8 + 7] + B[c + 7];
        *reinterpret_cast<float4*>(Y + (size_t)gr * DOUT + c) = o0;
        *reinterpret_cast<float4*>(Y + (size_t)gr * DOUT + c + 4) = o1;
      }
    }
  }
}

// Attention: one wave per dst node; 4x 16-lane groups, each with its own
// online-softmax over a strided slice of the edge list + 1-edge prefetch.
// NEG_INF_SAFE (not -inf) so empty-group merges never produce inf-inf = NaN.
#define NEG_BIG (-1e30f)
template <int DOUT, bool RELU>
__global__ __launch_bounds__(256) void attn_kernel(
    const float* __restrict__ xl, const float* __restrict__ xr,
    const float* __restrict__ att, const float* __restrict__ bias,
    const int* __restrict__ row_ptr, const int* __restrict__ col_src,
    float* __restrict__ out, int M) {
  constexpr int NQ = DOUT / 64;  // float4 chunks per lane (16 lanes x 4 floats)
  int wid = (int)((blockIdx.x * blockDim.x + threadIdx.x) >> 6);
  int lane = threadIdx.x & 63;
  int grp = lane >> 4;
  int sl = lane & 15;
  if (wid >= M) return;

  float attr[NQ * 4], xrr[NQ * 4], acc[NQ * 4];
#pragma unroll
  for (int q = 0; q < NQ; ++q) {
    float4 a4 = *reinterpret_cast<const float4*>(att + q * 64 + sl * 4);
    float4 r4 =
        *reinterpret_cast<const float4*>(xr + (size_t)wid * DOUT + q * 64 + sl * 4);
    attr[q * 4 + 0] = a4.x; attr[q * 4 + 1] = a4.y;
    attr[q * 4 + 2] = a4.z; attr[q * 4 + 3] = a4.w;
    xrr[q * 4 + 0] = r4.x; xrr[q * 4 + 1] = r4.y;
    xrr[q * 4 + 2] = r4.z; xrr[q * 4 + 3] = r4.w;
    acc[q * 4 + 0] = 0.f; acc[q * 4 + 1] = 0.f;
    acc[q * 4 + 2] = 0.f; acc[q * 4 + 3] = 0.f;
  }
  float m = NEG_BIG, s = 0.f;
  int e0 = row_ptr[wid], e1 = row_ptr[wid + 1];
  int j = e0 + grp;
  float4 xv[NQ], xn[NQ];
#pragma unroll
  for (int q = 0; q < NQ; ++q) {
    xv[q] = make_float4(0.f, 0.f, 0.f, 0.f);
    xn[q] = make_float4(0.f, 0.f, 0.f, 0.f);
  }
  if (j < e1) {
    int src = col_src[j];
    const float* rp = xl + (size_t)src * DOUT + sl * 4;
#pragma unroll
    for (int q = 0; q < NQ; ++q)
      xv[q] = *reinterpret_cast<const float4*>(rp + q * 64);
  }
  while (j < e1) {
    int jn = j + 4;
    if (jn < e1) {  // prefetch next edge's row while we reduce this one
      int srcn = col_src[jn];
      const float* rp = xl + (size_t)srcn * DOUT + sl * 4;
#pragma unroll
      for (int q = 0; q < NQ; ++q)
        xn[q] = *reinterpret_cast<const float4*>(rp + q * 64);
    }
    float p = 0.f;
#pragma unroll
    for (int q = 0; q < NQ; ++q) {
      float t0 = xv[q].x + xrr[q * 4 + 0];
      float t1 = xv[q].y + xrr[q * 4 + 1];
      float t2 = xv[q].z + xrr[q * 4 + 2];
      float t3 = xv[q].w + xrr[q * 4 + 3];
      t0 = fmaxf(t0, 0.2f * t0);
      t1 = fmaxf(t1, 0.2f * t1);
      t2 = fmaxf(t2, 0.2f * t2);
      t3 = fmaxf(t3, 0.2f * t3);
      p = fmaf(attr[q * 4 + 0], t0, p);
      p = fmaf(attr[q * 4 + 1], t1, p);
      p = fmaf(attr[q * 4 + 2], t2, p);
      p = fmaf(attr[q * 4 + 3], t3, p);
    }
#pragma unroll
    for (int off = 1; off < 16; off <<= 1) p += __shfl_xor(p, off, 64);
    float nm = fmaxf(m, p);
    float sc = __expf(m - nm);
    float pe = __expf(p - nm);
    s = s * sc + pe;
#pragma unroll
    for (int q = 0; q < NQ; ++q) {
      acc[q * 4 + 0] = fmaf(acc[q * 4 + 0], sc, pe * xv[q].x);
      acc[q * 4 + 1] = fmaf(acc[q * 4 + 1], sc, pe * xv[q].y);
      acc[q * 4 + 2] = fmaf(acc[q * 4 + 2], sc, pe * xv[q].z);
      acc[q * 4 + 3] = fmaf(acc[q * 4 + 3], sc, pe * xv[q].w);
    }
    m = nm;
#pragma unroll
    for (int q = 0; q < NQ; ++q) xv[q] = xn[q];
    j = jn;
  }
  // merge (m, s) across the 4 groups
  float mg = m;
  float mm = m, ss = s;
#pragma unroll
  for (int off = 16; off < 64; off <<= 1) {
    float mo = __shfl_xor(mm, off, 64);
    float so = __shfl_xor(ss, off, 64);
    float nm = fmaxf(mm, mo);
    ss = ss * __expf(mm - nm) + so * __expf(mo - nm);
    mm = nm;
  }
  float scale = __expf(mg - mm) / ss;  // ss > 0 (deg >= 1 via self-loop)
#pragma unroll
  for (int i = 0; i < NQ * 4; ++i) {
    float v = acc[i] * scale;
#pragma unroll
    for (int off = 16; off < 64; off <<= 1) v += __shfl_xor(v, off, 64);
    acc[i] = v;
  }
  // chunk q written by group (q & 3)
#pragma unroll
  for (int q = 0; q < NQ; ++q) {
    if (grp == (q & 3)) {
      int c = q * 64 + sl * 4;
      float4 b4 = *reinterpret_cast<const float4*>(bias + c);
      float4 o;
      o.x = acc[q * 4 + 0] + b4.x;
      o.y = acc[q * 4 + 1] + b4.y;
      o.z = acc[q * 4 + 2] + b4.z;
      o.w = acc[q * 4 + 3] + b4.w;
      if (RELU) {
        o.x = fmaxf(o.x, 0.f); o.y = fmaxf(o.y, 0.f);
        o.z = fmaxf(o.z, 0.f); o.w = fmaxf(o.w, 0.f);
      }
      *reinterpret_cast<float4*>(out + (size_t)wid * DOUT + c) = o;
    }
  }
}

// out[M][40] = H[M][256] @ WC[256][40] + BC.  One wave per row.
__global__ __launch_bounds__(256) void classifier_kernel(
    const float* __restrict__ H, const float* __restrict__ WC,
    const float* __restrict__ BC, float* __restrict__ out, int M) {
  __shared__ float rb[4][260];
  int wl = threadIdx.x >> 6;
  int lane = threadIdx.x & 63;
  int row = blockIdx.x * 4 + wl;
  bool valid = row < M;
  const float* hr = H + (size_t)(valid ? row : 0) * 256;
  float4 v = valid ? *reinterpret_cast<const float4*>(hr + lane * 4)
                   : make_float4(0.f, 0.f, 0.f, 0.f);
  *reinterpret_cast<float4*>(&rb[wl][lane * 4]) = v;
  __syncthreads();
  if (valid && lane < 40) {
    float acc = 0.f;
#pragma unroll 8
    for (int k = 0; k < 256; ++k) acc = fmaf(rb[wl][k], WC[k * 40 + lane], acc);
    out[(size_t)row * 40 + lane] = acc + BC[lane];
  }
}

extern "C" void kernel_launch(void* const* d_in, const int* in_sizes, int n_in,
                              void* d_out, int out_size, void* d_ws,
                              size_t ws_size, hipStream_t stream) {
  const float* x = (const float*)d_in[0];
  const int* ei = (const int*)d_in[1];
  const float* w1l = (const float*)d_in[2];
  const float* b1l = (const float*)d_in[3];
  const float* w1r = (const float*)d_in[4];
  const float* b1r = (const float*)d_in[5];
  const float* a1 = (const float*)d_in[6];
  const float* o1 = (const float*)d_in[7];
  const float* w2l = (const float*)d_in[8];
  const float* b2l = (const float*)d_in[9];
  const float* w2r = (const float*)d_in[10];
  const float* b2r = (const float*)d_in[11];
  const float* a2 = (const float*)d_in[12];
  const float* o2 = (const float*)d_in[13];
  const float* w3l = (const float*)d_in[14];
  const float* b3l = (const float*)d_in[15];
  const float* w3r = (const float*)d_in[16];
  const float* b3r = (const float*)d_in[17];
  const float* a3 = (const float*)d_in[18];
  const float* o3 = (const float*)d_in[19];
  const float* wc = (const float*)d_in[20];
  const float* bc = (const float*)d_in[21];
  float* out = (float*)d_out;

  const int n = in_sizes[0] / 128;  // 50000
  const int E = in_sizes[1] / 2;    // 800000
  const int tot = E + n;
  const int nchunks = (n + 1023) / 1024;  // 49 (<= 64 required)

  // workspace layout
  char* p = (char*)d_ws;
  int* row_ptr = (int*)p; p += (size_t)(n + 1) * 4;
  int* deg = (int*)p;     p += (size_t)n * 4;
  int* cursor = (int*)p;  p += (size_t)n * 4;
  int* partial = (int*)p; p += (size_t)64 * 4;
  int* col_src = (int*)p; p += (size_t)tot * 4;
  p = (char*)(((uintptr_t)p + 255) & ~(uintptr_t)255);
  float* bufA = (float*)p; p += (size_t)n * 256 * 4;
  float* bufB = (float*)p; p += (size_t)n * 256 * 4;
  float* bufC = (float*)p;

  const int TPB = 256;

  // CSR build
  zero_int_kernel<<<(n + TPB - 1) / TPB, TPB, 0, stream>>>(deg, n);
  deg_count_kernel<<<(tot + TPB - 1) / TPB, TPB, 0, stream>>>(ei + E, E, n, deg);
  block_sum_kernel<<<nchunks, 256, 0, stream>>>(deg, n, partial);
  scan_partial_kernel<<<1, 64, 0, stream>>>(partial, nchunks);
  block_scan_kernel<<<nchunks, 1024, 0, stream>>>(deg, partial, row_ptr, cursor, n);
  scatter_kernel<<<(tot + TPB - 1) / TPB, TPB, 0, stream>>>(ei, ei + E, E, n,
                                                            cursor, col_src);

  const int gemmGrid = (n + 63) / 64;
  const int waveGrid = (n + 3) / 4;

  // Layer 1 (128 -> 128) + ReLU
  gemm128_bias_kernel<128><<<gemmGrid, TPB, 0, stream>>>(x, w1l, b1l, bufB, n);
  gemm128_bias_kernel<128><<<gemmGrid, TPB, 0, stream>>>(x, w1r, b1r, bufC, n);
  attn_kernel<128, true><<<waveGrid, TPB, 0, stream>>>(bufB, bufC, a1, o1,
                                                       row_ptr, col_src, bufA, n);
  // Layer 2 (128 -> 128) + ReLU
  gemm128_bias_kernel<128><<<gemmGrid, TPB, 0, stream>>>(bufA, w2l, b2l, bufB, n);
  gemm128_bias_kernel<128><<<gemmGrid, TPB, 0, stream>>>(bufA, w2r, b2r, bufC, n);
  attn_kernel<128, true><<<waveGrid, TPB, 0, stream>>>(bufB, bufC, a2, o2,
                                                       row_ptr, col_src, bufA, n);
  // Layer 3 (128 -> 256), no ReLU
  gemm128_bias_kernel<256><<<gemmGrid, TPB, 0, stream>>>(bufA, w3l, b3l, bufB, n);
  gemm128_bias_kernel<256><<<gemmGrid, TPB, 0, stream>>>(bufA, w3r, b3r, bufC, n);
  attn_kernel<256, false><<<waveGrid, TPB, 0, stream>>>(bufB, bufC, a3, o3,
                                                        row_ptr, col_src, bufA, n);
  // Classifier (256 -> 40)
  classifier_kernel<<<waveGrid, TPB, 0, stream>>>(bufA, wc, bc, out, n);
}

// Round 3
// 598.475 us; speedup vs baseline: 1.4552x; 1.1329x over previous
//
#include <hip/hip_runtime.h>
#include <math.h>
#include <stdint.h>

// ---------------------------------------------------------------------------
// GATv2 3-layer network on MI355X.
//   1) CSR build by dst (deg count -> 3-kernel scan -> scatter).
//   2) Weights pre-packed into MFMA B-fragment order as bf16 hi/lo pairs.
//   3) Per layer: ONE fused MFMA kernel computes xl=h@Wl+bl AND xr=h@Wr+br
//      via split-bf16 (Xh*Wh + Xh*Wl + Xl*Wh ~ fp32 accuracy), then attention:
//      one wave per dst node, 4x 16-lane edge groups with online softmax.
//   4) Classifier GEMV per row.
// ---------------------------------------------------------------------------

typedef __attribute__((ext_vector_type(8))) short bf16x8;
typedef __attribute__((ext_vector_type(4))) float f32x4;
typedef unsigned short ushort_t;

__device__ inline ushort_t bf16_rne(float f) {
  unsigned u = __float_as_uint(f);
  unsigned r = (u + 0x7FFFu + ((u >> 16) & 1u)) >> 16;
  return (ushort_t)r;
}
__device__ inline float bf16_to_f(ushort_t h) {
  return __uint_as_float(((unsigned)h) << 16);
}

__global__ void zero_int_kernel(int* __restrict__ p, int n) {
  int i = blockIdx.x * blockDim.x + threadIdx.x;
  if (i < n) p[i] = 0;
}

__global__ void deg_count_kernel(const int* __restrict__ dst, int E, int n,
                                 int* __restrict__ deg) {
  int i = blockIdx.x * blockDim.x + threadIdx.x;
  int tot = E + n;
  if (i < tot) {
    int d = (i < E) ? dst[i] : (i - E);
    atomicAdd(&deg[d], 1);
  }
}

// 3-phase exclusive scan over deg[n], chunk=1024. nchunks must be <= 64.
__global__ __launch_bounds__(256) void block_sum_kernel(
    const int* __restrict__ deg, int n, int* __restrict__ partial) {
  __shared__ int sm[256];
  int base = blockIdx.x * 1024;
  int t = threadIdx.x;
  int sum = 0;
#pragma unroll
  for (int k = 0; k < 4; ++k) {
    int i = base + k * 256 + t;
    sum += (i < n) ? deg[i] : 0;
  }
  sm[t] = sum;
  __syncthreads();
  for (int off = 128; off > 0; off >>= 1) {
    if (t < off) sm[t] += sm[t + off];
    __syncthreads();
  }
  if (t == 0) partial[blockIdx.x] = sm[0];
}

__global__ void scan_partial_kernel(int* __restrict__ partial, int nchunks) {
  int lane = threadIdx.x;  // 64 threads
  int v = (lane < nchunks) ? partial[lane] : 0;
#pragma unroll
  for (int off = 1; off < 64; off <<= 1) {
    int u = __shfl_up(v, off, 64);
    if (lane >= off) v += u;
  }
  int ex = __shfl_up(v, 1, 64);
  if (lane == 0) ex = 0;
  if (lane < nchunks) partial[lane] = ex;
}

__global__ __launch_bounds__(1024) void block_scan_kernel(
    const int* __restrict__ deg, const int* __restrict__ partial,
    int* __restrict__ row_ptr, int* __restrict__ cursor, int n) {
  __shared__ int sm[1024];
  int i = blockIdx.x * 1024 + threadIdx.x;
  int v = (i < n) ? deg[i] : 0;
  sm[threadIdx.x] = v;
  __syncthreads();
  for (int off = 1; off < 1024; off <<= 1) {
    int t = (threadIdx.x >= off) ? sm[threadIdx.x - off] : 0;
    __syncthreads();
    sm[threadIdx.x] += t;
    __syncthreads();
  }
  int excl = partial[blockIdx.x] + sm[threadIdx.x] - v;
  if (i < n) {
    row_ptr[i] = excl;
    cursor[i] = excl;
  }
  if (i == n - 1) row_ptr[n] = excl + v;
}

__global__ void scatter_kernel(const int* __restrict__ src,
                               const int* __restrict__ dst, int E, int n,
                               int* __restrict__ cursor,
                               int* __restrict__ col_src) {
  int i = blockIdx.x * blockDim.x + threadIdx.x;
  int tot = E + n;
  if (i < tot) {
    int s = (i < E) ? src[i] : (i - E);
    int d = (i < E) ? dst[i] : (i - E);
    int slot = atomicAdd(&cursor[d], 1);
    col_src[slot] = s;
  }
}

// --------------------------- weight packing --------------------------------
// Fragment order for mfma_f32_16x16x32_bf16 B operand:
//   idx = ((ks*ntiles + t)*64 + lane)*8 + i  ->  W[ks*32 + 8*(lane>>4)+i][16t + (lane&15)]
struct PackArgs {
  const float* w[6];
  ushort_t* hi[6];
  ushort_t* lo[6];
  int ntiles[6];
  int N[6];
};

__global__ __launch_bounds__(256) void pack_w_kernel(PackArgs a) {
  int m = blockIdx.y;
  int ntiles = a.ntiles[m];
  int N = a.N[m];
  int tot = 4 * ntiles * 512;
  int idx = blockIdx.x * 256 + threadIdx.x;
  if (idx >= tot) return;
  int i = idx & 7;
  int lane = (idx >> 3) & 63;
  int t = (idx >> 9) % ntiles;
  int ks = idx / (512 * ntiles);
  int k = ks * 32 + (lane >> 4) * 8 + i;
  int c = t * 16 + (lane & 15);
  float f = a.w[m][k * N + c];
  ushort_t h = bf16_rne(f);
  a.hi[m][idx] = h;
  a.lo[m][idx] = bf16_rne(f - bf16_to_f(h));
}

// ----------------------- fused dual MFMA GEMM ------------------------------
// Yl = X@Wl+Bl, Yr = X@Wr+Br.  X: [M][128] fp32.  W pre-packed bf16 hi/lo.
// Block: 256 thr = 4 waves; wave handles 16 rows x 128 cols (8 16x16 tiles).
// grid.y selects a 128-col panel (for N=256).
__global__ __launch_bounds__(256) void gemm_dual_mfma(
    const float* __restrict__ X, const ushort_t* __restrict__ wlhi,
    const ushort_t* __restrict__ wllo, const ushort_t* __restrict__ wrhi,
    const ushort_t* __restrict__ wrlo, const float* __restrict__ Bl,
    const float* __restrict__ Br, float* __restrict__ Yl,
    float* __restrict__ Yr, int M, int N, int ntot) {
  int lane = threadIdx.x & 63;
  int wv = threadIdx.x >> 6;
  int kg = lane >> 4;   // 0..3
  int li = lane & 15;
  int rbase = blockIdx.x * 64 + wv * 16;
  int colofs = blockIdx.y * 128;
  int tbase = colofs >> 4;
  int arow = rbase + li;
  int ar = (arow < M) ? arow : (M - 1);
  const float* xp = X + (size_t)ar * 128 + kg * 8;

  f32x4 accl[8], accr[8];
#pragma unroll
  for (int t = 0; t < 8; ++t) {
    accl[t] = (f32x4){0.f, 0.f, 0.f, 0.f};
    accr[t] = (f32x4){0.f, 0.f, 0.f, 0.f};
  }

#pragma unroll
  for (int ks = 0; ks < 4; ++ks) {
    float4 a0 = *reinterpret_cast<const float4*>(xp + ks * 32);
    float4 a1 = *reinterpret_cast<const float4*>(xp + ks * 32 + 4);
    float av[8] = {a0.x, a0.y, a0.z, a0.w, a1.x, a1.y, a1.z, a1.w};
    bf16x8 ah, al;
#pragma unroll
    for (int i = 0; i < 8; ++i) {
      ushort_t h = bf16_rne(av[i]);
      ah[i] = (short)h;
      al[i] = (short)bf16_rne(av[i] - bf16_to_f(h));
    }
    size_t fb = ((size_t)ks * ntot + tbase) * 512 + (size_t)lane * 8;
#pragma unroll
    for (int t = 0; t < 8; ++t) {
      size_t o = fb + (size_t)t * 512;
      bf16x8 blh = *reinterpret_cast<const bf16x8*>(wlhi + o);
      bf16x8 bll = *reinterpret_cast<const bf16x8*>(wllo + o);
      bf16x8 brh = *reinterpret_cast<const bf16x8*>(wrhi + o);
      bf16x8 brl = *reinterpret_cast<const bf16x8*>(wrlo + o);
      accl[t] = __builtin_amdgcn_mfma_f32_16x16x32_bf16(ah, blh, accl[t], 0, 0, 0);
      accl[t] = __builtin_amdgcn_mfma_f32_16x16x32_bf16(ah, bll, accl[t], 0, 0, 0);
      accl[t] = __builtin_amdgcn_mfma_f32_16x16x32_bf16(al, blh, accl[t], 0, 0, 0);
      accr[t] = __builtin_amdgcn_mfma_f32_16x16x32_bf16(ah, brh, accr[t], 0, 0, 0);
      accr[t] = __builtin_amdgcn_mfma_f32_16x16x32_bf16(ah, brl, accr[t], 0, 0, 0);
      accr[t] = __builtin_amdgcn_mfma_f32_16x16x32_bf16(al, brh, accr[t], 0, 0, 0);
    }
  }
  // D layout: row = 4*(lane>>4)+reg, col = 16t + (lane&15)
  int srow = rbase + kg * 4;
#pragma unroll
  for (int t = 0; t < 8; ++t) {
    int col = colofs + t * 16 + li;
    float bl = Bl[col];
    float br = Br[col];
#pragma unroll
    for (int r = 0; r < 4; ++r) {
      int rr = srow + r;
      if (rr < M) {
        Yl[(size_t)rr * N + col] = accl[t][r] + bl;
        Yr[(size_t)rr * N + col] = accr[t][r] + br;
      }
    }
  }
}

// --------------------------- attention -------------------------------------
// One wave per dst node; 4x 16-lane groups, each with its own online-softmax
// over a strided slice of the edge list + 1-edge prefetch.
#define NEG_BIG (-1e30f)
template <int DOUT, bool RELU>
__global__ __launch_bounds__(256) void attn_kernel(
    const float* __restrict__ xl, const float* __restrict__ xr,
    const float* __restrict__ att, const float* __restrict__ bias,
    const int* __restrict__ row_ptr, const int* __restrict__ col_src,
    float* __restrict__ out, int M) {
  constexpr int NQ = DOUT / 64;
  int wid = (int)((blockIdx.x * blockDim.x + threadIdx.x) >> 6);
  int lane = threadIdx.x & 63;
  int grp = lane >> 4;
  int sl = lane & 15;
  if (wid >= M) return;

  float attr[NQ * 4], xrr[NQ * 4], acc[NQ * 4];
#pragma unroll
  for (int q = 0; q < NQ; ++q) {
    float4 a4 = *reinterpret_cast<const float4*>(att + q * 64 + sl * 4);
    float4 r4 =
        *reinterpret_cast<const float4*>(xr + (size_t)wid * DOUT + q * 64 + sl * 4);
    attr[q * 4 + 0] = a4.x; attr[q * 4 + 1] = a4.y;
    attr[q * 4 + 2] = a4.z; attr[q * 4 + 3] = a4.w;
    xrr[q * 4 + 0] = r4.x; xrr[q * 4 + 1] = r4.y;
    xrr[q * 4 + 2] = r4.z; xrr[q * 4 + 3] = r4.w;
    acc[q * 4 + 0] = 0.f; acc[q * 4 + 1] = 0.f;
    acc[q * 4 + 2] = 0.f; acc[q * 4 + 3] = 0.f;
  }
  float m = NEG_BIG, s = 0.f;
  int e0 = row_ptr[wid], e1 = row_ptr[wid + 1];
  int j = e0 + grp;
  float4 xv[NQ], xn[NQ];
#pragma unroll
  for (int q = 0; q < NQ; ++q) {
    xv[q] = make_float4(0.f, 0.f, 0.f, 0.f);
    xn[q] = make_float4(0.f, 0.f, 0.f, 0.f);
  }
  if (j < e1) {
    int src = col_src[j];
    const float* rp = xl + (size_t)src * DOUT + sl * 4;
#pragma unroll
    for (int q = 0; q < NQ; ++q)
      xv[q] = *reinterpret_cast<const float4*>(rp + q * 64);
  }
  while (j < e1) {
    int jn = j + 4;
    if (jn < e1) {
      int srcn = col_src[jn];
      const float* rp = xl + (size_t)srcn * DOUT + sl * 4;
#pragma unroll
      for (int q = 0; q < NQ; ++q)
        xn[q] = *reinterpret_cast<const float4*>(rp + q * 64);
    }
    float p = 0.f;
#pragma unroll
    for (int q = 0; q < NQ; ++q) {
      float t0 = xv[q].x + xrr[q * 4 + 0];
      float t1 = xv[q].y + xrr[q * 4 + 1];
      float t2 = xv[q].z + xrr[q * 4 + 2];
      float t3 = xv[q].w + xrr[q * 4 + 3];
      t0 = fmaxf(t0, 0.2f * t0);
      t1 = fmaxf(t1, 0.2f * t1);
      t2 = fmaxf(t2, 0.2f * t2);
      t3 = fmaxf(t3, 0.2f * t3);
      p = fmaf(attr[q * 4 + 0], t0, p);
      p = fmaf(attr[q * 4 + 1], t1, p);
      p = fmaf(attr[q * 4 + 2], t2, p);
      p = fmaf(attr[q * 4 + 3], t3, p);
    }
#pragma unroll
    for (int off = 1; off < 16; off <<= 1) p += __shfl_xor(p, off, 64);
    float nm = fmaxf(m, p);
    float sc = __expf(m - nm);
    float pe = __expf(p - nm);
    s = s * sc + pe;
#pragma unroll
    for (int q = 0; q < NQ; ++q) {
      acc[q * 4 + 0] = fmaf(acc[q * 4 + 0], sc, pe * xv[q].x);
      acc[q * 4 + 1] = fmaf(acc[q * 4 + 1], sc, pe * xv[q].y);
      acc[q * 4 + 2] = fmaf(acc[q * 4 + 2], sc, pe * xv[q].z);
      acc[q * 4 + 3] = fmaf(acc[q * 4 + 3], sc, pe * xv[q].w);
    }
    m = nm;
#pragma unroll
    for (int q = 0; q < NQ; ++q) xv[q] = xn[q];
    j = jn;
  }
  float mg = m;
  float mm = m, ss = s;
#pragma unroll
  for (int off = 16; off < 64; off <<= 1) {
    float mo = __shfl_xor(mm, off, 64);
    float so = __shfl_xor(ss, off, 64);
    float nm = fmaxf(mm, mo);
    ss = ss * __expf(mm - nm) + so * __expf(mo - nm);
    mm = nm;
  }
  float scale = __expf(mg - mm) / ss;
#pragma unroll
  for (int i = 0; i < NQ * 4; ++i) {
    float v = acc[i] * scale;
#pragma unroll
    for (int off = 16; off < 64; off <<= 1) v += __shfl_xor(v, off, 64);
    acc[i] = v;
  }
#pragma unroll
  for (int q = 0; q < NQ; ++q) {
    if (grp == (q & 3)) {
      int c = q * 64 + sl * 4;
      float4 b4 = *reinterpret_cast<const float4*>(bias + c);
      float4 o;
      o.x = acc[q * 4 + 0] + b4.x;
      o.y = acc[q * 4 + 1] + b4.y;
      o.z = acc[q * 4 + 2] + b4.z;
      o.w = acc[q * 4 + 3] + b4.w;
      if (RELU) {
        o.x = fmaxf(o.x, 0.f); o.y = fmaxf(o.y, 0.f);
        o.z = fmaxf(o.z, 0.f); o.w = fmaxf(o.w, 0.f);
      }
      *reinterpret_cast<float4*>(out + (size_t)wid * DOUT + c) = o;
    }
  }
}

// out[M][40] = H[M][256] @ WC[256][40] + BC.  One wave per row.
__global__ __launch_bounds__(256) void classifier_kernel(
    const float* __restrict__ H, const float* __restrict__ WC,
    const float* __restrict__ BC, float* __restrict__ out, int M) {
  __shared__ float rb[4][260];
  int wl = threadIdx.x >> 6;
  int lane = threadIdx.x & 63;
  int row = blockIdx.x * 4 + wl;
  bool valid = row < M;
  const float* hr = H + (size_t)(valid ? row : 0) * 256;
  float4 v = valid ? *reinterpret_cast<const float4*>(hr + lane * 4)
                   : make_float4(0.f, 0.f, 0.f, 0.f);
  *reinterpret_cast<float4*>(&rb[wl][lane * 4]) = v;
  __syncthreads();
  if (valid && lane < 40) {
    float acc = 0.f;
#pragma unroll 8
    for (int k = 0; k < 256; ++k) acc = fmaf(rb[wl][k], WC[k * 40 + lane], acc);
    out[(size_t)row * 40 + lane] = acc + BC[lane];
  }
}

extern "C" void kernel_launch(void* const* d_in, const int* in_sizes, int n_in,
                              void* d_out, int out_size, void* d_ws,
                              size_t ws_size, hipStream_t stream) {
  const float* x = (const float*)d_in[0];
  const int* ei = (const int*)d_in[1];
  const float* w1l = (const float*)d_in[2];
  const float* b1l = (const float*)d_in[3];
  const float* w1r = (const float*)d_in[4];
  const float* b1r = (const float*)d_in[5];
  const float* a1 = (const float*)d_in[6];
  const float* o1 = (const float*)d_in[7];
  const float* w2l = (const float*)d_in[8];
  const float* b2l = (const float*)d_in[9];
  const float* w2r = (const float*)d_in[10];
  const float* b2r = (const float*)d_in[11];
  const float* a2 = (const float*)d_in[12];
  const float* o2 = (const float*)d_in[13];
  const float* w3l = (const float*)d_in[14];
  const float* b3l = (const float*)d_in[15];
  const float* w3r = (const float*)d_in[16];
  const float* b3r = (const float*)d_in[17];
  const float* a3 = (const float*)d_in[18];
  const float* o3 = (const float*)d_in[19];
  const float* wc = (const float*)d_in[20];
  const float* bc = (const float*)d_in[21];
  float* out = (float*)d_out;

  const int n = in_sizes[0] / 128;  // 50000
  const int E = in_sizes[1] / 2;    // 800000
  const int tot = E + n;
  const int nchunks = (n + 1023) / 1024;  // <= 64 required

  // workspace layout
  char* p = (char*)d_ws;
  int* row_ptr = (int*)p; p += (size_t)(n + 1) * 4;
  int* deg = (int*)p;     p += (size_t)n * 4;
  int* cursor = (int*)p;  p += (size_t)n * 4;
  int* partial = (int*)p; p += (size_t)64 * 4;
  int* col_src = (int*)p; p += (size_t)tot * 4;
  p = (char*)(((uintptr_t)p + 255) & ~(uintptr_t)255);
  // packed weights: layers 1,2: 4*8*512 = 16384 elems per array; layer 3: 32768
  const size_t SZ12 = 16384, SZ3 = 32768;
  ushort_t* pk[12];
  for (int i = 0; i < 8; ++i) { pk[i] = (ushort_t*)p; p += SZ12 * 2; }
  for (int i = 8; i < 12; ++i) { pk[i] = (ushort_t*)p; p += SZ3 * 2; }
  p = (char*)(((uintptr_t)p + 255) & ~(uintptr_t)255);
  float* bufA = (float*)p; p += (size_t)n * 256 * 4;
  float* bufB = (float*)p; p += (size_t)n * 256 * 4;
  float* bufC = (float*)p;

  const int TPB = 256;

  // CSR build
  zero_int_kernel<<<(n + TPB - 1) / TPB, TPB, 0, stream>>>(deg, n);
  deg_count_kernel<<<(tot + TPB - 1) / TPB, TPB, 0, stream>>>(ei + E, E, n, deg);
  block_sum_kernel<<<nchunks, 256, 0, stream>>>(deg, n, partial);
  scan_partial_kernel<<<1, 64, 0, stream>>>(partial, nchunks);
  block_scan_kernel<<<nchunks, 1024, 0, stream>>>(deg, partial, row_ptr, cursor, n);
  scatter_kernel<<<(tot + TPB - 1) / TPB, TPB, 0, stream>>>(ei, ei + E, E, n,
                                                            cursor, col_src);

  // pack 6 weight matrices into MFMA B-fragment hi/lo arrays
  PackArgs pa;
  pa.w[0] = w1l; pa.w[1] = w1r; pa.w[2] = w2l; pa.w[3] = w2r;
  pa.w[4] = w3l; pa.w[5] = w3r;
  pa.hi[0] = pk[0]; pa.lo[0] = pk[1];
  pa.hi[1] = pk[2]; pa.lo[1] = pk[3];
  pa.hi[2] = pk[4]; pa.lo[2] = pk[5];
  pa.hi[3] = pk[6]; pa.lo[3] = pk[7];
  pa.hi[4] = pk[8]; pa.lo[4] = pk[9];
  pa.hi[5] = pk[10]; pa.lo[5] = pk[11];
  pa.ntiles[0] = pa.ntiles[1] = pa.ntiles[2] = pa.ntiles[3] = 8;
  pa.ntiles[4] = pa.ntiles[5] = 16;
  pa.N[0] = pa.N[1] = pa.N[2] = pa.N[3] = 128;
  pa.N[4] = pa.N[5] = 256;
  pack_w_kernel<<<dim3(128, 6), 256, 0, stream>>>(pa);

  const int gemmGrid = (n + 63) / 64;  // 782
  const int waveGrid = (n + 3) / 4;

  // Layer 1 (128 -> 128) + ReLU
  gemm_dual_mfma<<<dim3(gemmGrid, 1), TPB, 0, stream>>>(
      x, pk[0], pk[1], pk[2], pk[3], b1l, b1r, bufB, bufC, n, 128, 8);
  attn_kernel<128, true><<<waveGrid, TPB, 0, stream>>>(bufB, bufC, a1, o1,
                                                       row_ptr, col_src, bufA, n);
  // Layer 2 (128 -> 128) + ReLU
  gemm_dual_mfma<<<dim3(gemmGrid, 1), TPB, 0, stream>>>(
      bufA, pk[4], pk[5], pk[6], pk[7], b2l, b2r, bufB, bufC, n, 128, 8);
  attn_kernel<128, true><<<waveGrid, TPB, 0, stream>>>(bufB, bufC, a2, o2,
                                                       row_ptr, col_src, bufA, n);
  // Layer 3 (128 -> 256), no ReLU
  gemm_dual_mfma<<<dim3(gemmGrid, 2), TPB, 0, stream>>>(
      bufA, pk[8], pk[9], pk[10], pk[11], b3l, b3r, bufB, bufC, n, 256, 16);
  attn_kernel<256, false><<<waveGrid, TPB, 0, stream>>>(bufB, bufC, a3, o3,
                                                        row_ptr, col_src, bufA, n);
  // Classifier (256 -> 40)
  classifier_kernel<<<waveGrid, TPB, 0, stream>>>(bufA, wc, bc, out, n);
}

// Round 4
// 528.522 us; speedup vs baseline: 1.6478x; 1.1324x over previous
//
#include <hip/hip_runtime.h>
#include <math.h>
#include <stdint.h>

// ---------------------------------------------------------------------------
// GATv2 3-layer network on MI355X.
//   1) CSR build by dst (deg count -> 3-kernel scan -> scatter).
//   2) Weights pre-packed into MFMA B-fragment order as bf16 hi/lo pairs.
//   3) Per layer: ONE fused MFMA kernel computes xl=h@Wl+bl (emitted fp16,
//      consumed only by attention gather) AND xr=h@Wr+br (fp32), via
//      split-bf16 (Xh*Wh + Xh*Wl + Xl*Wh ~ fp32 accuracy). Then attention:
//      one wave per dst node, 4x 16-lane edge groups, online softmax,
//      2 gathers in flight + index prefetch.
//   4) Classifier GEMV per row.
// ---------------------------------------------------------------------------

typedef __attribute__((ext_vector_type(8))) short bf16x8;
typedef __attribute__((ext_vector_type(4))) float f32x4;
typedef __attribute__((ext_vector_type(4))) _Float16 half4;
typedef unsigned short ushort_t;

__device__ inline ushort_t bf16_rne(float f) {
  unsigned u = __float_as_uint(f);
  unsigned r = (u + 0x7FFFu + ((u >> 16) & 1u)) >> 16;
  return (ushort_t)r;
}
__device__ inline float bf16_to_f(ushort_t h) {
  return __uint_as_float(((unsigned)h) << 16);
}

__global__ void zero_int_kernel(int* __restrict__ p, int n) {
  int i = blockIdx.x * blockDim.x + threadIdx.x;
  if (i < n) p[i] = 0;
}

__global__ void deg_count_kernel(const int* __restrict__ dst, int E, int n,
                                 int* __restrict__ deg) {
  int i = blockIdx.x * blockDim.x + threadIdx.x;
  int tot = E + n;
  if (i < tot) {
    int d = (i < E) ? dst[i] : (i - E);
    atomicAdd(&deg[d], 1);
  }
}

// 3-phase exclusive scan over deg[n], chunk=1024. nchunks must be <= 64.
__global__ __launch_bounds__(256) void block_sum_kernel(
    const int* __restrict__ deg, int n, int* __restrict__ partial) {
  __shared__ int sm[256];
  int base = blockIdx.x * 1024;
  int t = threadIdx.x;
  int sum = 0;
#pragma unroll
  for (int k = 0; k < 4; ++k) {
    int i = base + k * 256 + t;
    sum += (i < n) ? deg[i] : 0;
  }
  sm[t] = sum;
  __syncthreads();
  for (int off = 128; off > 0; off >>= 1) {
    if (t < off) sm[t] += sm[t + off];
    __syncthreads();
  }
  if (t == 0) partial[blockIdx.x] = sm[0];
}

__global__ void scan_partial_kernel(int* __restrict__ partial, int nchunks) {
  int lane = threadIdx.x;  // 64 threads
  int v = (lane < nchunks) ? partial[lane] : 0;
#pragma unroll
  for (int off = 1; off < 64; off <<= 1) {
    int u = __shfl_up(v, off, 64);
    if (lane >= off) v += u;
  }
  int ex = __shfl_up(v, 1, 64);
  if (lane == 0) ex = 0;
  if (lane < nchunks) partial[lane] = ex;
}

__global__ __launch_bounds__(1024) void block_scan_kernel(
    const int* __restrict__ deg, const int* __restrict__ partial,
    int* __restrict__ row_ptr, int* __restrict__ cursor, int n) {
  __shared__ int sm[1024];
  int i = blockIdx.x * 1024 + threadIdx.x;
  int v = (i < n) ? deg[i] : 0;
  sm[threadIdx.x] = v;
  __syncthreads();
  for (int off = 1; off < 1024; off <<= 1) {
    int t = (threadIdx.x >= off) ? sm[threadIdx.x - off] : 0;
    __syncthreads();
    sm[threadIdx.x] += t;
    __syncthreads();
  }
  int excl = partial[blockIdx.x] + sm[threadIdx.x] - v;
  if (i < n) {
    row_ptr[i] = excl;
    cursor[i] = excl;
  }
  if (i == n - 1) row_ptr[n] = excl + v;
}

__global__ void scatter_kernel(const int* __restrict__ src,
                               const int* __restrict__ dst, int E, int n,
                               int* __restrict__ cursor,
                               int* __restrict__ col_src) {
  int i = blockIdx.x * blockDim.x + threadIdx.x;
  int tot = E + n;
  if (i < tot) {
    int s = (i < E) ? src[i] : (i - E);
    int d = (i < E) ? dst[i] : (i - E);
    int slot = atomicAdd(&cursor[d], 1);
    col_src[slot] = s;
  }
}

// --------------------------- weight packing --------------------------------
// Fragment order for mfma_f32_16x16x32_bf16 B operand:
//   idx = ((ks*ntiles + t)*64 + lane)*8 + i -> W[ks*32+8*(lane>>4)+i][16t+(lane&15)]
struct PackArgs {
  const float* w[6];
  ushort_t* hi[6];
  ushort_t* lo[6];
  int ntiles[6];
  int N[6];
};

__global__ __launch_bounds__(256) void pack_w_kernel(PackArgs a) {
  int m = blockIdx.y;
  int ntiles = a.ntiles[m];
  int N = a.N[m];
  int tot = 4 * ntiles * 512;
  int idx = blockIdx.x * 256 + threadIdx.x;
  if (idx >= tot) return;
  int i = idx & 7;
  int lane = (idx >> 3) & 63;
  int t = (idx >> 9) % ntiles;
  int ks = idx / (512 * ntiles);
  int k = ks * 32 + (lane >> 4) * 8 + i;
  int c = t * 16 + (lane & 15);
  float f = a.w[m][k * N + c];
  ushort_t h = bf16_rne(f);
  a.hi[m][idx] = h;
  a.lo[m][idx] = bf16_rne(f - bf16_to_f(h));
}

// ----------------------- fused dual MFMA GEMM ------------------------------
// Yl (fp16) = X@Wl+Bl, Yr (fp32) = X@Wr+Br.  X: [M][128] fp32.
// Block: 256 thr = 4 waves; wave handles 16 rows x 128 cols (8 16x16 tiles).
// grid.y selects a 128-col panel (for N=256).
__global__ __launch_bounds__(256) void gemm_dual_mfma(
    const float* __restrict__ X, const ushort_t* __restrict__ wlhi,
    const ushort_t* __restrict__ wllo, const ushort_t* __restrict__ wrhi,
    const ushort_t* __restrict__ wrlo, const float* __restrict__ Bl,
    const float* __restrict__ Br, _Float16* __restrict__ Yl,
    float* __restrict__ Yr, int M, int N, int ntot) {
  int lane = threadIdx.x & 63;
  int wv = threadIdx.x >> 6;
  int kg = lane >> 4;  // 0..3
  int li = lane & 15;
  int rbase = blockIdx.x * 64 + wv * 16;
  int colofs = blockIdx.y * 128;
  int tbase = colofs >> 4;
  int arow = rbase + li;
  int ar = (arow < M) ? arow : (M - 1);
  const float* xp = X + (size_t)ar * 128 + kg * 8;

  f32x4 accl[8], accr[8];
#pragma unroll
  for (int t = 0; t < 8; ++t) {
    accl[t] = (f32x4){0.f, 0.f, 0.f, 0.f};
    accr[t] = (f32x4){0.f, 0.f, 0.f, 0.f};
  }

#pragma unroll
  for (int ks = 0; ks < 4; ++ks) {
    float4 a0 = *reinterpret_cast<const float4*>(xp + ks * 32);
    float4 a1 = *reinterpret_cast<const float4*>(xp + ks * 32 + 4);
    float av[8] = {a0.x, a0.y, a0.z, a0.w, a1.x, a1.y, a1.z, a1.w};
    bf16x8 ah, al;
#pragma unroll
    for (int i = 0; i < 8; ++i) {
      ushort_t h = bf16_rne(av[i]);
      ah[i] = (short)h;
      al[i] = (short)bf16_rne(av[i] - bf16_to_f(h));
    }
    size_t fb = ((size_t)ks * ntot + tbase) * 512 + (size_t)lane * 8;
#pragma unroll
    for (int t = 0; t < 8; ++t) {
      size_t o = fb + (size_t)t * 512;
      bf16x8 blh = *reinterpret_cast<const bf16x8*>(wlhi + o);
      bf16x8 bll = *reinterpret_cast<const bf16x8*>(wllo + o);
      bf16x8 brh = *reinterpret_cast<const bf16x8*>(wrhi + o);
      bf16x8 brl = *reinterpret_cast<const bf16x8*>(wrlo + o);
      accl[t] = __builtin_amdgcn_mfma_f32_16x16x32_bf16(ah, blh, accl[t], 0, 0, 0);
      accl[t] = __builtin_amdgcn_mfma_f32_16x16x32_bf16(ah, bll, accl[t], 0, 0, 0);
      accl[t] = __builtin_amdgcn_mfma_f32_16x16x32_bf16(al, blh, accl[t], 0, 0, 0);
      accr[t] = __builtin_amdgcn_mfma_f32_16x16x32_bf16(ah, brh, accr[t], 0, 0, 0);
      accr[t] = __builtin_amdgcn_mfma_f32_16x16x32_bf16(ah, brl, accr[t], 0, 0, 0);
      accr[t] = __builtin_amdgcn_mfma_f32_16x16x32_bf16(al, brh, accr[t], 0, 0, 0);
    }
  }
  // D layout: row = 4*(lane>>4)+reg, col = 16t + (lane&15)
  int srow = rbase + kg * 4;
#pragma unroll
  for (int t = 0; t < 8; ++t) {
    int col = colofs + t * 16 + li;
    float bl = Bl[col];
    float br = Br[col];
#pragma unroll
    for (int r = 0; r < 4; ++r) {
      int rr = srow + r;
      if (rr < M) {
        Yl[(size_t)rr * N + col] = (_Float16)(accl[t][r] + bl);
        Yr[(size_t)rr * N + col] = accr[t][r] + br;
      }
    }
  }
}

// --------------------------- attention -------------------------------------
// One wave per dst node; 4x 16-lane groups, each with its own online-softmax
// over a strided slice of the edge list. fp16 gather payload; 2 gathers in
// flight per group + edge index prefetched a further iteration ahead.
#define NEG_BIG (-1e30f)
template <int DOUT, bool RELU>
__global__ __launch_bounds__(256) void attn_kernel(
    const _Float16* __restrict__ xl, const float* __restrict__ xr,
    const float* __restrict__ att, const float* __restrict__ bias,
    const int* __restrict__ row_ptr, const int* __restrict__ col_src,
    float* __restrict__ out, int M) {
  constexpr int NQ = DOUT / 64;
  int wid = (int)((blockIdx.x * blockDim.x + threadIdx.x) >> 6);
  int lane = threadIdx.x & 63;
  int grp = lane >> 4;
  int sl = lane & 15;
  if (wid >= M) return;

  float attr[NQ * 4], xrr[NQ * 4], acc[NQ * 4];
#pragma unroll
  for (int q = 0; q < NQ; ++q) {
    float4 a4 = *reinterpret_cast<const float4*>(att + q * 64 + sl * 4);
    float4 r4 =
        *reinterpret_cast<const float4*>(xr + (size_t)wid * DOUT + q * 64 + sl * 4);
    attr[q * 4 + 0] = a4.x; attr[q * 4 + 1] = a4.y;
    attr[q * 4 + 2] = a4.z; attr[q * 4 + 3] = a4.w;
    xrr[q * 4 + 0] = r4.x; xrr[q * 4 + 1] = r4.y;
    xrr[q * 4 + 2] = r4.z; xrr[q * 4 + 3] = r4.w;
    acc[q * 4 + 0] = 0.f; acc[q * 4 + 1] = 0.f;
    acc[q * 4 + 2] = 0.f; acc[q * 4 + 3] = 0.f;
  }
  float m = NEG_BIG, s = 0.f;
  int e0 = row_ptr[wid], e1 = row_ptr[wid + 1];
  int j = e0 + grp;  // this group's edge stream: j, j+4, j+8, ...

  half4 xv[NQ], xn[NQ], x2[NQ];
#pragma unroll
  for (int q = 0; q < NQ; ++q) {
    xv[q] = (half4)0;
    xn[q] = (half4)0;
    x2[q] = (half4)0;
  }
  // prologue: gathers for edges j, j+4 in flight; index for j+8 in register.
  if (j < e1) {
    const half4* rp = reinterpret_cast<const half4*>(xl) +
                      (size_t)col_src[j] * (DOUT / 4) + sl;
#pragma unroll
    for (int q = 0; q < NQ; ++q) xv[q] = rp[q * 16];
  }
  if (j + 4 < e1) {
    const half4* rp = reinterpret_cast<const half4*>(xl) +
                      (size_t)col_src[j + 4] * (DOUT / 4) + sl;
#pragma unroll
    for (int q = 0; q < NQ; ++q) xn[q] = rp[q * 16];
  }
  int i2 = (j + 8 < e1) ? col_src[j + 8] : 0;

  while (j < e1) {
    int i3 = (j + 12 < e1) ? col_src[j + 12] : 0;  // index prefetch
    if (j + 8 < e1) {  // issue gather for edge j+8 (2 in flight)
      const half4* rp =
          reinterpret_cast<const half4*>(xl) + (size_t)i2 * (DOUT / 4) + sl;
#pragma unroll
      for (int q = 0; q < NQ; ++q) x2[q] = rp[q * 16];
    }
    // score for edge j from xv
    float p = 0.f;
    float xf[NQ * 4];
#pragma unroll
    for (int q = 0; q < NQ; ++q) {
      xf[q * 4 + 0] = (float)xv[q].x;
      xf[q * 4 + 1] = (float)xv[q].y;
      xf[q * 4 + 2] = (float)xv[q].z;
      xf[q * 4 + 3] = (float)xv[q].w;
#pragma unroll
      for (int u = 0; u < 4; ++u) {
        float t = xf[q * 4 + u] + xrr[q * 4 + u];
        t = fmaxf(t, 0.2f * t);  // leaky_relu 0.2
        p = fmaf(attr[q * 4 + u], t, p);
      }
    }
#pragma unroll
    for (int off = 1; off < 16; off <<= 1) p += __shfl_xor(p, off, 64);
    float nm = fmaxf(m, p);
    float sc = __expf(m - nm);
    float pe = __expf(p - nm);
    s = s * sc + pe;
#pragma unroll
    for (int i = 0; i < NQ * 4; ++i) acc[i] = fmaf(acc[i], sc, pe * xf[i]);
    m = nm;
#pragma unroll
    for (int q = 0; q < NQ; ++q) {
      xv[q] = xn[q];
      xn[q] = x2[q];
    }
    i2 = i3;
    j += 4;
  }
  // merge (m, s) across the 4 groups
  float mg = m;
  float mm = m, ss = s;
#pragma unroll
  for (int off = 16; off < 64; off <<= 1) {
    float mo = __shfl_xor(mm, off, 64);
    float so = __shfl_xor(ss, off, 64);
    float nm = fmaxf(mm, mo);
    ss = ss * __expf(mm - nm) + so * __expf(mo - nm);
    mm = nm;
  }
  float scale = __expf(mg - mm) / ss;  // ss > 0 (deg >= 1 via self-loop)
#pragma unroll
  for (int i = 0; i < NQ * 4; ++i) {
    float v = acc[i] * scale;
#pragma unroll
    for (int off = 16; off < 64; off <<= 1) v += __shfl_xor(v, off, 64);
    acc[i] = v;
  }
  // chunk q written by group (q & 3)
#pragma unroll
  for (int q = 0; q < NQ; ++q) {
    if (grp == (q & 3)) {
      int c = q * 64 + sl * 4;
      float4 b4 = *reinterpret_cast<const float4*>(bias + c);
      float4 o;
      o.x = acc[q * 4 + 0] + b4.x;
      o.y = acc[q * 4 + 1] + b4.y;
      o.z = acc[q * 4 + 2] + b4.z;
      o.w = acc[q * 4 + 3] + b4.w;
      if (RELU) {
        o.x = fmaxf(o.x, 0.f); o.y = fmaxf(o.y, 0.f);
        o.z = fmaxf(o.z, 0.f); o.w = fmaxf(o.w, 0.f);
      }
      *reinterpret_cast<float4*>(out + (size_t)wid * DOUT + c) = o;
    }
  }
}

// out[M][40] = H[M][256] @ WC[256][40] + BC.  One wave per row.
__global__ __launch_bounds__(256) void classifier_kernel(
    const float* __restrict__ H, const float* __restrict__ WC,
    const float* __restrict__ BC, float* __restrict__ out, int M) {
  __shared__ float rb[4][260];
  int wl = threadIdx.x >> 6;
  int lane = threadIdx.x & 63;
  int row = blockIdx.x * 4 + wl;
  bool valid = row < M;
  const float* hr = H + (size_t)(valid ? row : 0) * 256;
  float4 v = valid ? *reinterpret_cast<const float4*>(hr + lane * 4)
                   : make_float4(0.f, 0.f, 0.f, 0.f);
  *reinterpret_cast<float4*>(&rb[wl][lane * 4]) = v;
  __syncthreads();
  if (valid && lane < 40) {
    float acc = 0.f;
#pragma unroll 8
    for (int k = 0; k < 256; ++k) acc = fmaf(rb[wl][k], WC[k * 40 + lane], acc);
    out[(size_t)row * 40 + lane] = acc + BC[lane];
  }
}

extern "C" void kernel_launch(void* const* d_in, const int* in_sizes, int n_in,
                              void* d_out, int out_size, void* d_ws,
                              size_t ws_size, hipStream_t stream) {
  const float* x = (const float*)d_in[0];
  const int* ei = (const int*)d_in[1];
  const float* w1l = (const float*)d_in[2];
  const float* b1l = (const float*)d_in[3];
  const float* w1r = (const float*)d_in[4];
  const float* b1r = (const float*)d_in[5];
  const float* a1 = (const float*)d_in[6];
  const float* o1 = (const float*)d_in[7];
  const float* w2l = (const float*)d_in[8];
  const float* b2l = (const float*)d_in[9];
  const float* w2r = (const float*)d_in[10];
  const float* b2r = (const float*)d_in[11];
  const float* a2 = (const float*)d_in[12];
  const float* o2 = (const float*)d_in[13];
  const float* w3l = (const float*)d_in[14];
  const float* b3l = (const float*)d_in[15];
  const float* w3r = (const float*)d_in[16];
  const float* b3r = (const float*)d_in[17];
  const float* a3 = (const float*)d_in[18];
  const float* o3 = (const float*)d_in[19];
  const float* wc = (const float*)d_in[20];
  const float* bc = (const float*)d_in[21];
  float* out = (float*)d_out;

  const int n = in_sizes[0] / 128;  // 50000
  const int E = in_sizes[1] / 2;    // 800000
  const int tot = E + n;
  const int nchunks = (n + 1023) / 1024;  // <= 64 required

  // workspace layout
  char* p = (char*)d_ws;
  int* row_ptr = (int*)p; p += (size_t)(n + 1) * 4;
  int* deg = (int*)p;     p += (size_t)n * 4;
  int* cursor = (int*)p;  p += (size_t)n * 4;
  int* partial = (int*)p; p += (size_t)64 * 4;
  int* col_src = (int*)p; p += (size_t)tot * 4;
  p = (char*)(((uintptr_t)p + 255) & ~(uintptr_t)255);
  // packed weights: layers 1,2: 16384 elems per array; layer 3: 32768
  const size_t SZ12 = 16384, SZ3 = 32768;
  ushort_t* pk[12];
  for (int i = 0; i < 8; ++i) { pk[i] = (ushort_t*)p; p += SZ12 * 2; }
  for (int i = 8; i < 12; ++i) { pk[i] = (ushort_t*)p; p += SZ3 * 2; }
  p = (char*)(((uintptr_t)p + 255) & ~(uintptr_t)255);
  float* bufA = (float*)p;          p += (size_t)n * 256 * 4;  // attn out / next in
  _Float16* bufL = (_Float16*)p;    p += (size_t)n * 256 * 2;  // xl (fp16)
  float* bufR = (float*)p;                                      // xr (fp32)

  const int TPB = 256;

  // CSR build
  zero_int_kernel<<<(n + TPB - 1) / TPB, TPB, 0, stream>>>(deg, n);
  deg_count_kernel<<<(tot + TPB - 1) / TPB, TPB, 0, stream>>>(ei + E, E, n, deg);
  block_sum_kernel<<<nchunks, 256, 0, stream>>>(deg, n, partial);
  scan_partial_kernel<<<1, 64, 0, stream>>>(partial, nchunks);
  block_scan_kernel<<<nchunks, 1024, 0, stream>>>(deg, partial, row_ptr, cursor, n);
  scatter_kernel<<<(tot + TPB - 1) / TPB, TPB, 0, stream>>>(ei, ei + E, E, n,
                                                            cursor, col_src);

  // pack 6 weight matrices into MFMA B-fragment hi/lo arrays
  PackArgs pa;
  pa.w[0] = w1l; pa.w[1] = w1r; pa.w[2] = w2l; pa.w[3] = w2r;
  pa.w[4] = w3l; pa.w[5] = w3r;
  pa.hi[0] = pk[0]; pa.lo[0] = pk[1];
  pa.hi[1] = pk[2]; pa.lo[1] = pk[3];
  pa.hi[2] = pk[4]; pa.lo[2] = pk[5];
  pa.hi[3] = pk[6]; pa.lo[3] = pk[7];
  pa.hi[4] = pk[8]; pa.lo[4] = pk[9];
  pa.hi[5] = pk[10]; pa.lo[5] = pk[11];
  pa.ntiles[0] = pa.ntiles[1] = pa.ntiles[2] = pa.ntiles[3] = 8;
  pa.ntiles[4] = pa.ntiles[5] = 16;
  pa.N[0] = pa.N[1] = pa.N[2] = pa.N[3] = 128;
  pa.N[4] = pa.N[5] = 256;
  pack_w_kernel<<<dim3(128, 6), 256, 0, stream>>>(pa);

  const int gemmGrid = (n + 63) / 64;
  const int waveGrid = (n + 3) / 4;

  // Layer 1 (128 -> 128) + ReLU
  gemm_dual_mfma<<<dim3(gemmGrid, 1), TPB, 0, stream>>>(
      x, pk[0], pk[1], pk[2], pk[3], b1l, b1r, bufL, bufR, n, 128, 8);
  attn_kernel<128, true><<<waveGrid, TPB, 0, stream>>>(bufL, bufR, a1, o1,
                                                       row_ptr, col_src, bufA, n);
  // Layer 2 (128 -> 128) + ReLU
  gemm_dual_mfma<<<dim3(gemmGrid, 1), TPB, 0, stream>>>(
      bufA, pk[4], pk[5], pk[6], pk[7], b2l, b2r, bufL, bufR, n, 128, 8);
  attn_kernel<128, true><<<waveGrid, TPB, 0, stream>>>(bufL, bufR, a2, o2,
                                                       row_ptr, col_src, bufA, n);
  // Layer 3 (128 -> 256), no ReLU
  gemm_dual_mfma<<<dim3(gemmGrid, 2), TPB, 0, stream>>>(
      bufA, pk[8], pk[9], pk[10], pk[11], b3l, b3r, bufL, bufR, n, 256, 16);
  attn_kernel<256, false><<<waveGrid, TPB, 0, stream>>>(bufL, bufR, a3, o3,
                                                        row_ptr, col_src, bufA, n);
  // Classifier (256 -> 40)
  classifier_kernel<<<waveGrid, TPB, 0, stream>>>(bufA, wc, bc, out, n);
}